// Round 2
// baseline (231.161 us; speedup 1.0000x reference)
//
#include <hip/hip_runtime.h>
#include <hip/hip_bf16.h>

#define NB 256      // batch
#define NA 64       // atoms
#define NG 978      // genes
#define CELL_IN 978
#define DOSE_IN 12
#define GLOBAL_F 306
#define EXP_IN 434
#define NE 4

// ---------------------------------------------------------------------------
// K1: per-batch encoders (drug-sum, cell MLP, dose MLP), concat g, gating
// top-2 softmax. One block per batch element, 256 threads. All fp32.
// ---------------------------------------------------------------------------
__global__ __launch_bounds__(256) void encoder_kernel(
    const float* __restrict__ drug, const float* __restrict__ gex,
    const float* __restrict__ idose,
    const float* __restrict__ cW1, const float* __restrict__ cb1,
    const float* __restrict__ cW2, const float* __restrict__ cb2,
    const float* __restrict__ cW3, const float* __restrict__ cb3,
    const float* __restrict__ dW1, const float* __restrict__ db1,
    const float* __restrict__ dW2, const float* __restrict__ db2,
    const float* __restrict__ gW1, const float* __restrict__ gb1,
    const float* __restrict__ gW2, const float* __restrict__ gb2,
    float* __restrict__ g_out, float* __restrict__ gates_out,
    float* __restrict__ cell_out)
{
    __shared__ float s_gex[CELL_IN];
    __shared__ float s_g[GLOBAL_F];   // [drug 0:128 | cell 128:178 | dose 178:306]
    __shared__ float s_h1[200];
    __shared__ float s_h2[100];
    __shared__ float s_d1[64];
    __shared__ float s_gh[128];
    __shared__ float s_logit[NE];

    const int b = blockIdx.x, tid = threadIdx.x;

    for (int i = tid; i < CELL_IN; i += 256)
        s_gex[i] = gex[b * CELL_IN + i];
    if (tid < 128) {                      // drug = sum over atoms
        float acc = 0.f;
        const float* p = drug + (size_t)b * NA * 128 + tid;
        #pragma unroll 8
        for (int a = 0; a < NA; ++a) acc += p[a * 128];
        s_g[tid] = acc;
    }
    __syncthreads();

    // cell layer1: 978 -> 200
    if (tid < 200) {
        float acc = cb1[tid];
        for (int i = 0; i < CELL_IN; ++i)
            acc += s_gex[i] * cW1[i * 200 + tid];
        s_h1[tid] = fmaxf(acc, 0.f);
    }
    __syncthreads();

    // cell layer2: 200 -> 100  (threads 0..99); dose layer1: 12->64 (128..191)
    if (tid < 100) {
        float acc = cb2[tid];
        for (int i = 0; i < 200; ++i)
            acc += s_h1[i] * cW2[i * 100 + tid];
        s_h2[tid] = fmaxf(acc, 0.f);
    } else if (tid >= 128 && tid < 192) {
        int j = tid - 128;
        float acc = db1[j];
        for (int i = 0; i < DOSE_IN; ++i)
            acc += idose[b * DOSE_IN + i] * dW1[i * 64 + j];
        s_d1[j] = fmaxf(acc, 0.f);
    }
    __syncthreads();

    // cell layer3: 100 -> 50 (threads 0..49); dose layer2: 64->128 (64..191)
    if (tid < 50) {
        float acc = cb3[tid];
        for (int i = 0; i < 100; ++i)
            acc += s_h2[i] * cW3[i * 50 + tid];
        float r = fmaxf(acc, 0.f);
        s_g[128 + tid] = r;
        cell_out[b * 50 + tid] = r;
    } else if (tid >= 64 && tid < 192) {
        int j = tid - 64;
        float acc = db2[j];
        for (int i = 0; i < 64; ++i)
            acc += s_d1[i] * dW2[i * 128 + j];
        s_g[178 + j] = fmaxf(acc, 0.f);
    }
    __syncthreads();

    // write g; gate hidden: 306 -> 128 (relu)
    for (int i = tid; i < GLOBAL_F; i += 256)
        g_out[b * GLOBAL_F + i] = s_g[i];
    if (tid < 128) {
        float acc = gb1[tid];
        for (int i = 0; i < GLOBAL_F; ++i)
            acc += s_g[i] * gW1[i * 128 + tid];
        s_gh[tid] = fmaxf(acc, 0.f);
    }
    __syncthreads();

    // gate logits: 128 -> 4 (no relu)
    if (tid < NE) {
        float acc = gb2[tid];
        for (int i = 0; i < 128; ++i)
            acc += s_gh[i] * gW2[i * NE + tid];
        s_logit[tid] = acc;
    }
    __syncthreads();

    // top-2 + softmax -> sparse gates (first-index tie-break like lax.top_k)
    if (tid == 0) {
        int i1 = 0; float v1 = s_logit[0];
        #pragma unroll
        for (int i = 1; i < NE; ++i)
            if (s_logit[i] > v1) { v1 = s_logit[i]; i1 = i; }
        int i2 = -1; float v2 = -__builtin_inff();
        #pragma unroll
        for (int i = 0; i < NE; ++i) {
            if (i == i1) continue;
            if (s_logit[i] > v2) { v2 = s_logit[i]; i2 = i; }
        }
        float e2 = __expf(v2 - v1);
        float inv = 1.f / (1.f + e2);
        float out[NE] = {0.f, 0.f, 0.f, 0.f};
        out[i1] = inv;
        out[i2] = e2 * inv;
        #pragma unroll
        for (int i = 0; i < NE; ++i) gates_out[b * NE + i] = out[i];
    }
}

// ---------------------------------------------------------------------------
// K2: u[b,e,:] = g[b] @ exp_W1[e,:306,:] + exp_b1[e]   (no relu here)
// grid = B*E blocks of 128 threads
// ---------------------------------------------------------------------------
__global__ __launch_bounds__(128) void u_kernel(
    const float* __restrict__ gfeat, const float* __restrict__ eW1,
    const float* __restrict__ eb1, float* __restrict__ u)
{
    __shared__ float s_g[GLOBAL_F];
    const int be = blockIdx.x, b = be >> 2, e = be & 3, tid = threadIdx.x;
    for (int i = tid; i < GLOBAL_F; i += 128) s_g[i] = gfeat[b * GLOBAL_F + i];
    __syncthreads();
    float acc = eb1[e * 128 + tid];
    const float* w = eW1 + (size_t)e * EXP_IN * 128 + tid;
    for (int i = 0; i < GLOBAL_F; ++i) acc += s_g[i] * w[i * 128];
    u[(size_t)be * 128 + tid] = acc;
}

// ---------------------------------------------------------------------------
// K3: v[g,e,:] = gene_emb[g] @ exp_W1[e,306:434,:]
// grid = G*E blocks of 128 threads
// ---------------------------------------------------------------------------
__global__ __launch_bounds__(128) void v_kernel(
    const float* __restrict__ gene, const float* __restrict__ eW1,
    float* __restrict__ v)
{
    __shared__ float s_ge[128];
    const int geb = blockIdx.x, g = geb >> 2, e = geb & 3, tid = threadIdx.x;
    s_ge[tid] = gene[g * 128 + tid];
    __syncthreads();
    float acc = 0.f;
    const float* w = eW1 + ((size_t)e * EXP_IN + GLOBAL_F) * 128 + tid;
    for (int i = 0; i < 128; ++i) acc += s_ge[i] * w[i * 128];
    v[(size_t)geb * 128 + tid] = acc;
}

// ---------------------------------------------------------------------------
// K4: pred[b,g] = sum_e gates[b,e] * ( dot(relu(u[b,e]+v[g,e]), w2[e]) + b2[e] )
// Only the 2 experts with nonzero gate are computed (block-uniform branch).
// grid = B blocks of 256 threads.
// ---------------------------------------------------------------------------
__global__ __launch_bounds__(256) void final_kernel(
    const float* __restrict__ u, const float* __restrict__ v,
    const float* __restrict__ gates, const float* __restrict__ eW2,
    const float* __restrict__ eb2, float* __restrict__ pred)
{
    __shared__ float s_u[NE * 128];
    __shared__ float s_w2[NE * 128];
    __shared__ float s_gate[NE];
    __shared__ float s_b2[NE];
    const int b = blockIdx.x, tid = threadIdx.x;

    for (int k = tid; k < NE * 128; k += 256) {
        s_u[k]  = u[(size_t)b * NE * 128 + k];
        s_w2[k] = eW2[k];                // exp_W2 [E,128,1] flat = e*128+h
    }
    if (tid < NE) { s_gate[tid] = gates[b * NE + tid]; s_b2[tid] = eb2[tid]; }
    __syncthreads();

    for (int g = tid; g < NG; g += 256) {
        float acc = 0.f;
        #pragma unroll
        for (int e = 0; e < NE; ++e) {
            float ge = s_gate[e];
            if (ge != 0.f) {             // block-uniform branch
                const float4* vp = (const float4*)(v + ((size_t)g * NE + e) * 128);
                const float* up = s_u + e * 128;
                const float* wp = s_w2 + e * 128;
                float dot = 0.f;
                #pragma unroll
                for (int k = 0; k < 32; ++k) {
                    float4 vv = vp[k];
                    float t0 = fmaxf(up[4*k+0] + vv.x, 0.f);
                    float t1 = fmaxf(up[4*k+1] + vv.y, 0.f);
                    float t2 = fmaxf(up[4*k+2] + vv.z, 0.f);
                    float t3 = fmaxf(up[4*k+3] + vv.w, 0.f);
                    dot += t0 * wp[4*k+0] + t1 * wp[4*k+1]
                         + t2 * wp[4*k+2] + t3 * wp[4*k+3];
                }
                acc += ge * (dot + s_b2[e]);
            }
        }
        pred[b * NG + g] = acc;
    }
}

// ---------------------------------------------------------------------------
extern "C" void kernel_launch(void* const* d_in, const int* in_sizes, int n_in,
                              void* d_out, int out_size, void* d_ws, size_t ws_size,
                              hipStream_t stream) {
    const float* drug  = (const float*)d_in[0];
    const float* gex   = (const float*)d_in[1];
    const float* idose = (const float*)d_in[2];
    const float* cW1 = (const float*)d_in[3];  const float* cb1 = (const float*)d_in[4];
    const float* cW2 = (const float*)d_in[5];  const float* cb2 = (const float*)d_in[6];
    const float* cW3 = (const float*)d_in[7];  const float* cb3 = (const float*)d_in[8];
    const float* dW1 = (const float*)d_in[9];  const float* db1 = (const float*)d_in[10];
    const float* dW2 = (const float*)d_in[11]; const float* db2 = (const float*)d_in[12];
    const float* gene = (const float*)d_in[13];
    const float* gW1 = (const float*)d_in[14]; const float* gb1 = (const float*)d_in[15];
    const float* gW2 = (const float*)d_in[16]; const float* gb2 = (const float*)d_in[17];
    const float* eW1 = (const float*)d_in[18]; const float* eb1 = (const float*)d_in[19];
    const float* eW2 = (const float*)d_in[20]; const float* eb2 = (const float*)d_in[21];

    // fp32 workspace layout (elements):
    //   g_feat [B*306] | gates [B*4] | u [B*4*128] | v [G*4*128]  -> ~2.85 MB
    float* ws     = (float*)d_ws;
    float* g_feat = ws;
    float* gates  = g_feat + NB * GLOBAL_F;
    float* u      = gates + NB * NE;
    float* v      = u + (size_t)NB * NE * 128;

    float* out  = (float*)d_out;
    float* pred = out;              // [B, G]
    float* cell = out + NB * NG;    // [B, 50]

    // v does not depend on encoder output — launch it first for overlap headroom
    v_kernel<<<NG * NE, 128, 0, stream>>>(gene, eW1, v);
    encoder_kernel<<<NB, 256, 0, stream>>>(drug, gex, idose,
        cW1, cb1, cW2, cb2, cW3, cb3, dW1, db1, dW2, db2,
        gW1, gb1, gW2, gb2, g_feat, gates, cell);
    u_kernel<<<NB * NE, 128, 0, stream>>>(g_feat, eW1, eb1, u);
    final_kernel<<<NB, 256, 0, stream>>>(u, v, gates, eW2, eb2, pred);
}